// Round 1
// baseline (205.175 us; speedup 1.0000x reference)
//
#include <hip/hip_runtime.h>
#include <hip/hip_bf16.h>

// MultiHeadAttention fused pipeline, round 0 (correctness-first, m97-style GEMMs)
// B=2 S=2048 D=1024 H=16 dk=64.
// ws layout (48 MB): Xb 8M | Wq/Wk/Wv/Wo bf16 2M each | Qb 8M | Kb 8M | Vt 8M | Ob 8M

typedef unsigned short u16;
typedef __attribute__((ext_vector_type(4))) unsigned short u16x4;
typedef __attribute__((ext_vector_type(8))) short short8;   // 8 x bf16 (4 VGPRs)
typedef __attribute__((ext_vector_type(4))) float f32x4;

__device__ __forceinline__ u16 f2bf(float f) {  // RNE float->bf16
  union { float f; unsigned u; } v; v.f = f;
  return (u16)((v.u + 0x7fffu + ((v.u >> 16) & 1u)) >> 16);
}

__device__ __forceinline__ f32x4 mfma_bf16(short8 a, short8 b, f32x4 c) {
  return __builtin_amdgcn_mfma_f32_16x16x32_bf16(a, b, c, 0, 0, 0);
}

#define GLL16(gp, lp) __builtin_amdgcn_global_load_lds( \
    (const __attribute__((address_space(1))) void*)(gp), \
    (__attribute__((address_space(3))) void*)(lp), 16, 0, 0)

// ---------------------------------------------------------------- casts
__global__ __launch_bounds__(256) void cast_all(
    const float* __restrict__ x,
    const float* __restrict__ wq, const float* __restrict__ wk,
    const float* __restrict__ wv, const float* __restrict__ wo,
    u16* __restrict__ xb, u16* __restrict__ wqb, u16* __restrict__ wkb,
    u16* __restrict__ wvb, u16* __restrict__ wob)
{
  const int z = blockIdx.z;
  const float* s; u16* d; int n4;
  if (z == 0)      { s = x;  d = xb;  n4 = 1048576; }
  else if (z == 1) { s = wq; d = wqb; n4 = 262144; }
  else if (z == 2) { s = wk; d = wkb; n4 = 262144; }
  else if (z == 3) { s = wv; d = wvb; n4 = 262144; }
  else             { s = wo; d = wob; n4 = 262144; }
  int i = blockIdx.x * 256 + threadIdx.x;
  if (i >= n4) return;
  float4 v = ((const float4*)s)[i];
  u16x4 o; o[0] = f2bf(v.x); o[1] = f2bf(v.y); o[2] = f2bf(v.z); o[3] = f2bf(v.w);
  ((u16x4*)d)[i] = o;
}

// -------------------------------------------------- 128x128 GEMM core, C = A * B^T
// A [M,1024] bf16 row-major, B [N,1024] bf16 row-major (W as stored: out = x @ W.T).
// 256 thr = 4 waves (2x2), each wave 64x64 = 4x4 frags of 16x16x32 MFMA.
// Staging: global_load_lds x4 per K-step (A 8KB + B 8KB), linear LDS [128][32].
__device__ __forceinline__ void gemm_core(const u16* __restrict__ A,
                                          const u16* __restrict__ B,
                                          u16* sA, u16* sB, f32x4 acc[4][4])
{
  const int tid = threadIdx.x;
  const int lane = tid & 63, wave = tid >> 6;
  const int wr = wave >> 1, wc = wave & 1;
  const int m0 = blockIdx.y * 128, n0 = blockIdx.x * 128;
  const u16* ga = A + (size_t)(m0 + (tid >> 2)) * 1024 + (tid & 3) * 8;
  const u16* gb = B + (size_t)(n0 + (tid >> 2)) * 1024 + (tid & 3) * 8;
  u16* la0 = sA + wave * 512;          u16* la1 = sA + 2048 + wave * 512;
  u16* lb0 = sB + wave * 512;          u16* lb1 = sB + 2048 + wave * 512;
  const int rl = lane & 15, kg = (lane >> 4) * 8;

  for (int k0 = 0; k0 < 1024; k0 += 32) {
    GLL16(ga + k0,             la0);
    GLL16(ga + 64 * 1024 + k0, la1);
    GLL16(gb + k0,             lb0);
    GLL16(gb + 64 * 1024 + k0, lb1);
    __syncthreads();
    short8 af[4], bf_[4];
#pragma unroll
    for (int m = 0; m < 4; ++m) af[m]  = *(const short8*)&sA[(wr * 64 + m * 16 + rl) * 32 + kg];
#pragma unroll
    for (int n = 0; n < 4; ++n) bf_[n] = *(const short8*)&sB[(wc * 64 + n * 16 + rl) * 32 + kg];
#pragma unroll
    for (int m = 0; m < 4; ++m)
#pragma unroll
      for (int n = 0; n < 4; ++n)
        acc[m][n] = mfma_bf16(af[m], bf_[n], acc[m][n]);
    __syncthreads();
  }
}

// QKV projections fused via blockIdx.z. z=0 -> Q (bf16 [4096][1024]),
// z=1 -> K (same layout), z=2 -> V written TRANSPOSED: Vt[(b*1024+hd)][s].
__global__ __launch_bounds__(256) void gemm_qkv(
    const u16* __restrict__ X,
    const u16* __restrict__ Wqb, const u16* __restrict__ Wkb, const u16* __restrict__ Wvb,
    const float* __restrict__ bq, const float* __restrict__ bk, const float* __restrict__ bv,
    u16* __restrict__ Qo, u16* __restrict__ Ko, u16* __restrict__ Vt)
{
  __shared__ u16 sA[4096], sB[4096];
  const int z = blockIdx.z;
  const u16* W = (z == 0) ? Wqb : (z == 1) ? Wkb : Wvb;
  const float* bias = (z == 0) ? bq : (z == 1) ? bk : bv;

  f32x4 acc[4][4];
#pragma unroll
  for (int m = 0; m < 4; ++m)
#pragma unroll
    for (int n = 0; n < 4; ++n) acc[m][n] = (f32x4){0.f, 0.f, 0.f, 0.f};

  gemm_core(X, W, sA, sB, acc);

  const int lane = threadIdx.x & 63, wave = threadIdx.x >> 6;
  const int wr = wave >> 1, wc = wave & 1;
  const int m0 = blockIdx.y * 128, n0 = blockIdx.x * 128;
  const int rl = lane & 15, rg = (lane >> 4) * 4;

  if (z < 2) {
    u16* dst = (z == 0) ? Qo : Ko;
#pragma unroll
    for (int n = 0; n < 4; ++n) {
      int col = n0 + wc * 64 + n * 16 + rl;
      float bb = bias[col];
#pragma unroll
      for (int m = 0; m < 4; ++m) {
        int row0 = m0 + wr * 64 + m * 16 + rg;
#pragma unroll
        for (int r = 0; r < 4; ++r)
          dst[(size_t)(row0 + r) * 1024 + col] = f2bf(acc[m][n][r] + bb);
      }
    }
  } else {
    // C-layout rows (s) are contiguous in r -> pack 4 bf16, transposed store is free
#pragma unroll
    for (int n = 0; n < 4; ++n) {
      int col = n0 + wc * 64 + n * 16 + rl;   // hd = h*64+d
      float bb = bias[col];
#pragma unroll
      for (int m = 0; m < 4; ++m) {
        int row0 = m0 + wr * 64 + m * 16 + rg;          // b*2048 + s
        int bidx = row0 >> 11, sl = row0 & 2047;
        u16x4 pk;
#pragma unroll
        for (int r = 0; r < 4; ++r) pk[r] = f2bf(acc[m][n][r] + bb);
        *(u16x4*)&Vt[((size_t)(bidx * 1024 + col)) * 2048 + sl] = pk;
      }
    }
  }
}

// Output projection: out(fp32) = Ob @ Wo^T + bo
__global__ __launch_bounds__(256) void gemm_out(
    const u16* __restrict__ Ob, const u16* __restrict__ Wob,
    const float* __restrict__ bo, float* __restrict__ Out)
{
  __shared__ u16 sA[4096], sB[4096];
  f32x4 acc[4][4];
#pragma unroll
  for (int m = 0; m < 4; ++m)
#pragma unroll
    for (int n = 0; n < 4; ++n) acc[m][n] = (f32x4){0.f, 0.f, 0.f, 0.f};

  gemm_core(Ob, Wob, sA, sB, acc);

  const int lane = threadIdx.x & 63, wave = threadIdx.x >> 6;
  const int wr = wave >> 1, wc = wave & 1;
  const int m0 = blockIdx.y * 128, n0 = blockIdx.x * 128;
  const int rl = lane & 15, rg = (lane >> 4) * 4;
#pragma unroll
  for (int n = 0; n < 4; ++n) {
    int col = n0 + wc * 64 + n * 16 + rl;
    float bb = bo[col];
#pragma unroll
    for (int m = 0; m < 4; ++m) {
      int row0 = m0 + wr * 64 + m * 16 + rg;
#pragma unroll
      for (int r = 0; r < 4; ++r)
        Out[(size_t)(row0 + r) * 1024 + col] = acc[m][n][r] + bb;
    }
  }
}

// ---------------------------------------------------------------- flash attention
// Swapped QK^T: S^T = mfma(K_frag, Q_frag) so each lane owns one q-column.
// K rows loaded PERMUTED (key = kt + 8*(x>>2) + 4t + (x&3)) so score C-regs
// [t][r] are exactly the PV B-operand k-order (k = 8g + 4t + r) -- no shuffles.
// Wave = 32 q rows (2 qgroups), block = 4 waves = 128 q rows. V read from Vt
// (transposed) so PV A-frags are contiguous-k 16B loads.
__global__ __launch_bounds__(256) void attn_fwd(
    const u16* __restrict__ Q, const u16* __restrict__ K,
    const u16* __restrict__ Vt, u16* __restrict__ O)
{
  const int tid = threadIdx.x, lane = tid & 63, wave = tid >> 6;
  const int rl = lane & 15, g = lane >> 4;
  const int bh = blockIdx.y, b = bh >> 4, h = bh & 15;
  const int qbase = blockIdx.x * 128 + wave * 32;

  const u16* Qp = Q + (size_t)(b * 2048 + qbase) * 1024 + h * 64;
  const u16* Kp = K + (size_t)(b * 2048) * 1024 + h * 64;
  const u16* Vp = Vt + (size_t)(bh * 64) * 2048;

  short8 qf[2][2];
#pragma unroll
  for (int qg = 0; qg < 2; ++qg)
#pragma unroll
    for (int hf = 0; hf < 2; ++hf)
      qf[qg][hf] = *(const short8*)&Qp[(size_t)(qg * 16 + rl) * 1024 + hf * 32 + g * 8];

  const int keyperm = 8 * (rl >> 2) + (rl & 3);

  f32x4 oacc[2][4];
#pragma unroll
  for (int qg = 0; qg < 2; ++qg)
#pragma unroll
    for (int dg = 0; dg < 4; ++dg) oacc[qg][dg] = (f32x4){0.f, 0.f, 0.f, 0.f};
  float mrun[2] = {-INFINITY, -INFINITY};
  float lrun[2] = {0.f, 0.f};

  for (int kt = 0; kt < 2048; kt += 32) {
    short8 kf[2][2];
#pragma unroll
    for (int t = 0; t < 2; ++t) {
      const u16* kr = Kp + (size_t)(kt + keyperm + 4 * t) * 1024;
#pragma unroll
      for (int hf = 0; hf < 2; ++hf)
        kf[t][hf] = *(const short8*)&kr[hf * 32 + g * 8];
    }
    short8 vf[4];                         // issue V loads early
#pragma unroll
    for (int dg = 0; dg < 4; ++dg)
      vf[dg] = *(const short8*)&Vp[(size_t)(dg * 16 + rl) * 2048 + kt + g * 8];

    f32x4 sc[2][2];
#pragma unroll
    for (int qg = 0; qg < 2; ++qg)
#pragma unroll
      for (int t = 0; t < 2; ++t) {
        f32x4 a = (f32x4){0.f, 0.f, 0.f, 0.f};
        a = mfma_bf16(kf[t][0], qf[qg][0], a);
        a = mfma_bf16(kf[t][1], qf[qg][1], a);
        sc[qg][t] = a;
      }

    short8 pb[2];
#pragma unroll
    for (int qg = 0; qg < 2; ++qg) {
      float p[8];
#pragma unroll
      for (int t = 0; t < 2; ++t)
#pragma unroll
        for (int r = 0; r < 4; ++r) p[t * 4 + r] = sc[qg][t][r] * 0.125f;
      float tm = p[0];
#pragma unroll
      for (int j = 1; j < 8; ++j) tm = fmaxf(tm, p[j]);
      tm = fmaxf(tm, __shfl_xor(tm, 16));
      tm = fmaxf(tm, __shfl_xor(tm, 32));
      float mnew = fmaxf(mrun[qg], tm);
      float sfac = __expf(mrun[qg] - mnew);
      mrun[qg] = mnew;
      float ts = 0.f;
#pragma unroll
      for (int j = 0; j < 8; ++j) { p[j] = __expf(p[j] - mnew); ts += p[j]; }
      ts += __shfl_xor(ts, 16);
      ts += __shfl_xor(ts, 32);
      lrun[qg] = lrun[qg] * sfac + ts;
#pragma unroll
      for (int dg = 0; dg < 4; ++dg)
#pragma unroll
        for (int r = 0; r < 4; ++r) oacc[qg][dg][r] *= sfac;
      short8 pk;
#pragma unroll
      for (int j = 0; j < 8; ++j) pk[j] = (short)f2bf(p[j]);
      pb[qg] = pk;
    }
#pragma unroll
    for (int dg = 0; dg < 4; ++dg)
#pragma unroll
      for (int qg = 0; qg < 2; ++qg)
        oacc[qg][dg] = mfma_bf16(vf[dg], pb[qg], oacc[qg][dg]);
  }

#pragma unroll
  for (int qg = 0; qg < 2; ++qg) {
    float inv = 1.0f / lrun[qg];
    int qrow = qbase + qg * 16 + rl;
    u16* op = O + (size_t)(b * 2048 + qrow) * 1024 + h * 64;
#pragma unroll
    for (int dg = 0; dg < 4; ++dg) {
      u16x4 pk;
#pragma unroll
      for (int r = 0; r < 4; ++r) pk[r] = f2bf(oacc[qg][dg][r] * inv);
      *(u16x4*)&op[dg * 16 + g * 4] = pk;
    }
  }
}

// ---------------------------------------------------------------- launch
extern "C" void kernel_launch(void* const* d_in, const int* in_sizes, int n_in,
                              void* d_out, int out_size, void* d_ws, size_t ws_size,
                              hipStream_t stream) {
  const float* x  = (const float*)d_in[0];
  const float* Wq = (const float*)d_in[1];
  const float* bq = (const float*)d_in[2];
  const float* Wk = (const float*)d_in[3];
  const float* bk = (const float*)d_in[4];
  const float* Wv = (const float*)d_in[5];
  const float* bv = (const float*)d_in[6];
  const float* Wo = (const float*)d_in[7];
  const float* bo = (const float*)d_in[8];

  char* ws = (char*)d_ws;
  const size_t MB = 1024 * 1024;
  u16* Xb  = (u16*)(ws + 0 * MB);
  u16* Wqb = (u16*)(ws + 8 * MB);
  u16* Wkb = (u16*)(ws + 10 * MB);
  u16* Wvb = (u16*)(ws + 12 * MB);
  u16* Wob = (u16*)(ws + 14 * MB);
  u16* Qb  = (u16*)(ws + 16 * MB);
  u16* Kb  = (u16*)(ws + 24 * MB);
  u16* Vtb = (u16*)(ws + 32 * MB);
  u16* Ob  = (u16*)(ws + 40 * MB);

  cast_all<<<dim3(4096, 1, 5), 256, 0, stream>>>(x, Wq, Wk, Wv, Wo,
                                                 Xb, Wqb, Wkb, Wvb, Wob);
  gemm_qkv<<<dim3(8, 32, 3), 256, 0, stream>>>(Xb, Wqb, Wkb, Wvb,
                                               bq, bk, bv, Qb, Kb, Vtb);
  attn_fwd<<<dim3(16, 32), 256, 0, stream>>>(Qb, Kb, Vtb, Ob);
  gemm_out<<<dim3(8, 32), 256, 0, stream>>>(Ob, Wob, bo, (float*)d_out);
}

// Round 2
// 189.673 us; speedup vs baseline: 1.0817x; 1.0817x over previous
//
#include <hip/hip_runtime.h>
#include <hip/hip_bf16.h>

// MultiHeadAttention fused pipeline, round 2: VALU-lean flash attention.
// B=2 S=2048 D=1024 H=16 dk=64.
// ws layout (48 MB): Xb 8M | Wq/Wk/Wv/Wo bf16 2M each | Qb 8M | Kb 8M | Vt 8M | Ob 8M
// Changes vs R1:
//  - Q pre-scaled by 0.125*log2(e) in gemm_qkv epilogue -> softmax in exp2 domain
//  - defer-max (THR=8): skip rescale/max-shuffles when tile max doesn't grow
//  - row-sum of P via MFMA with ones-vector (matrix pipe, not VALU)
//  - native bf16 cvt ((__bf16) cast -> v_cvt_pk_bf16_f32) everywhere
//  - register ping-pong double-buffer of K/V tiles

typedef unsigned short u16;
typedef __attribute__((ext_vector_type(4))) unsigned short u16x4;
typedef __attribute__((ext_vector_type(8))) short short8;   // 8 x bf16 (4 VGPRs)
typedef __attribute__((ext_vector_type(4))) float f32x4;

__device__ __forceinline__ u16 f2bf(float f) {  // native RNE f32->bf16
  __bf16 b = (__bf16)f;
  return __builtin_bit_cast(unsigned short, b);
}

__device__ __forceinline__ f32x4 mfma_bf16(short8 a, short8 b, f32x4 c) {
  return __builtin_amdgcn_mfma_f32_16x16x32_bf16(a, b, c, 0, 0, 0);
}

#define GLL16(gp, lp) __builtin_amdgcn_global_load_lds( \
    (const __attribute__((address_space(1))) void*)(gp), \
    (__attribute__((address_space(3))) void*)(lp), 16, 0, 0)

#define QSCALE 0.18033688011112042f   /* 0.125 * log2(e) */

// ---------------------------------------------------------------- casts
__global__ __launch_bounds__(256) void cast_all(
    const float* __restrict__ x,
    const float* __restrict__ wq, const float* __restrict__ wk,
    const float* __restrict__ wv, const float* __restrict__ wo,
    u16* __restrict__ xb, u16* __restrict__ wqb, u16* __restrict__ wkb,
    u16* __restrict__ wvb, u16* __restrict__ wob)
{
  const int z = blockIdx.z;
  const float* s; u16* d; int n4;
  if (z == 0)      { s = x;  d = xb;  n4 = 1048576; }
  else if (z == 1) { s = wq; d = wqb; n4 = 262144; }
  else if (z == 2) { s = wk; d = wkb; n4 = 262144; }
  else if (z == 3) { s = wv; d = wvb; n4 = 262144; }
  else             { s = wo; d = wob; n4 = 262144; }
  int i = blockIdx.x * 256 + threadIdx.x;
  if (i >= n4) return;
  float4 v = ((const float4*)s)[i];
  u16x4 o; o[0] = f2bf(v.x); o[1] = f2bf(v.y); o[2] = f2bf(v.z); o[3] = f2bf(v.w);
  ((u16x4*)d)[i] = o;
}

// -------------------------------------------------- 128x128 GEMM core, C = A * B^T
__device__ __forceinline__ void gemm_core(const u16* __restrict__ A,
                                          const u16* __restrict__ B,
                                          u16* sA, u16* sB, f32x4 acc[4][4])
{
  const int tid = threadIdx.x;
  const int lane = tid & 63, wave = tid >> 6;
  const int wr = wave >> 1, wc = wave & 1;
  const int m0 = blockIdx.y * 128, n0 = blockIdx.x * 128;
  const u16* ga = A + (size_t)(m0 + (tid >> 2)) * 1024 + (tid & 3) * 8;
  const u16* gb = B + (size_t)(n0 + (tid >> 2)) * 1024 + (tid & 3) * 8;
  u16* la0 = sA + wave * 512;          u16* la1 = sA + 2048 + wave * 512;
  u16* lb0 = sB + wave * 512;          u16* lb1 = sB + 2048 + wave * 512;
  const int rl = lane & 15, kg = (lane >> 4) * 8;

  for (int k0 = 0; k0 < 1024; k0 += 32) {
    GLL16(ga + k0,             la0);
    GLL16(ga + 64 * 1024 + k0, la1);
    GLL16(gb + k0,             lb0);
    GLL16(gb + 64 * 1024 + k0, lb1);
    __syncthreads();
    short8 af[4], bf_[4];
#pragma unroll
    for (int m = 0; m < 4; ++m) af[m]  = *(const short8*)&sA[(wr * 64 + m * 16 + rl) * 32 + kg];
#pragma unroll
    for (int n = 0; n < 4; ++n) bf_[n] = *(const short8*)&sB[(wc * 64 + n * 16 + rl) * 32 + kg];
#pragma unroll
    for (int m = 0; m < 4; ++m)
#pragma unroll
      for (int n = 0; n < 4; ++n)
        acc[m][n] = mfma_bf16(af[m], bf_[n], acc[m][n]);
    __syncthreads();
  }
}

// QKV projections fused via blockIdx.z. z=0 -> Q (PRE-SCALED by QSCALE),
// z=1 -> K, z=2 -> V written TRANSPOSED: Vt[(b*1024+hd)][s].
__global__ __launch_bounds__(256) void gemm_qkv(
    const u16* __restrict__ X,
    const u16* __restrict__ Wqb, const u16* __restrict__ Wkb, const u16* __restrict__ Wvb,
    const float* __restrict__ bq, const float* __restrict__ bk, const float* __restrict__ bv,
    u16* __restrict__ Qo, u16* __restrict__ Ko, u16* __restrict__ Vt)
{
  __shared__ u16 sA[4096], sB[4096];
  const int z = blockIdx.z;
  const u16* W = (z == 0) ? Wqb : (z == 1) ? Wkb : Wvb;
  const float* bias = (z == 0) ? bq : (z == 1) ? bk : bv;

  f32x4 acc[4][4];
#pragma unroll
  for (int m = 0; m < 4; ++m)
#pragma unroll
    for (int n = 0; n < 4; ++n) acc[m][n] = (f32x4){0.f, 0.f, 0.f, 0.f};

  gemm_core(X, W, sA, sB, acc);

  const int lane = threadIdx.x & 63, wave = threadIdx.x >> 6;
  const int wr = wave >> 1, wc = wave & 1;
  const int m0 = blockIdx.y * 128, n0 = blockIdx.x * 128;
  const int rl = lane & 15, rg = (lane >> 4) * 4;

  if (z < 2) {
    u16* dst = (z == 0) ? Qo : Ko;
    const float cs = (z == 0) ? QSCALE : 1.0f;
#pragma unroll
    for (int n = 0; n < 4; ++n) {
      int col = n0 + wc * 64 + n * 16 + rl;
      float bb = bias[col];
#pragma unroll
      for (int m = 0; m < 4; ++m) {
        int row0 = m0 + wr * 64 + m * 16 + rg;
#pragma unroll
        for (int r = 0; r < 4; ++r)
          dst[(size_t)(row0 + r) * 1024 + col] = f2bf((acc[m][n][r] + bb) * cs);
      }
    }
  } else {
#pragma unroll
    for (int n = 0; n < 4; ++n) {
      int col = n0 + wc * 64 + n * 16 + rl;   // hd = h*64+d
      float bb = bias[col];
#pragma unroll
      for (int m = 0; m < 4; ++m) {
        int row0 = m0 + wr * 64 + m * 16 + rg;          // b*2048 + s
        int bidx = row0 >> 11, sl = row0 & 2047;
        u16x4 pk;
#pragma unroll
        for (int r = 0; r < 4; ++r) pk[r] = f2bf(acc[m][n][r] + bb);
        *(u16x4*)&Vt[((size_t)(bidx * 1024 + col)) * 2048 + sl] = pk;
      }
    }
  }
}

// Output projection: out(fp32) = Ob @ Wo^T + bo
__global__ __launch_bounds__(256) void gemm_out(
    const u16* __restrict__ Ob, const u16* __restrict__ Wob,
    const float* __restrict__ bo, float* __restrict__ Out)
{
  __shared__ u16 sA[4096], sB[4096];
  f32x4 acc[4][4];
#pragma unroll
  for (int m = 0; m < 4; ++m)
#pragma unroll
    for (int n = 0; n < 4; ++n) acc[m][n] = (f32x4){0.f, 0.f, 0.f, 0.f};

  gemm_core(Ob, Wob, sA, sB, acc);

  const int lane = threadIdx.x & 63, wave = threadIdx.x >> 6;
  const int wr = wave >> 1, wc = wave & 1;
  const int m0 = blockIdx.y * 128, n0 = blockIdx.x * 128;
  const int rl = lane & 15, rg = (lane >> 4) * 4;
#pragma unroll
  for (int n = 0; n < 4; ++n) {
    int col = n0 + wc * 64 + n * 16 + rl;
    float bb = bo[col];
#pragma unroll
    for (int m = 0; m < 4; ++m) {
      int row0 = m0 + wr * 64 + m * 16 + rg;
#pragma unroll
      for (int r = 0; r < 4; ++r)
        Out[(size_t)(row0 + r) * 1024 + col] = acc[m][n][r] + bb;
    }
  }
}

// ---------------------------------------------------------------- flash attention
// Swapped QK^T (mfma(K,Q)): lane owns one q-column, 8 keys per tile.
// K rows loaded PERMUTED so score C-regs are exactly the PV B-operand k-order.
// Q pre-scaled by 0.125*log2e -> scores already in exp2 domain.
// Per wave: 32 q rows. Per block: 4 waves = 128 q rows.
__global__ __launch_bounds__(256) void attn_fwd(
    const u16* __restrict__ Q, const u16* __restrict__ K,
    const u16* __restrict__ Vt, u16* __restrict__ O)
{
  const int tid = threadIdx.x, lane = tid & 63, wave = tid >> 6;
  const int rl = lane & 15, g = lane >> 4;
  const int bh = blockIdx.y, b = bh >> 4, h = bh & 15;
  const int qbase = blockIdx.x * 128 + wave * 32;

  const u16* Qp = Q + (size_t)(b * 2048 + qbase) * 1024 + h * 64;
  const u16* Kp = K + (size_t)(b * 2048) * 1024 + h * 64;
  const u16* Vp = Vt + (size_t)(bh * 64) * 2048;

  short8 qf[2][2];
#pragma unroll
  for (int qg = 0; qg < 2; ++qg)
#pragma unroll
    for (int hf = 0; hf < 2; ++hf)
      qf[qg][hf] = *(const short8*)&Qp[(size_t)(qg * 16 + rl) * 1024 + hf * 32 + g * 8];

  const int keyperm = 8 * (rl >> 2) + (rl & 3);

  f32x4 oacc[2][4];
  f32x4 lacc[2];
#pragma unroll
  for (int qg = 0; qg < 2; ++qg) {
    lacc[qg] = (f32x4){0.f, 0.f, 0.f, 0.f};
#pragma unroll
    for (int dg = 0; dg < 4; ++dg) oacc[qg][dg] = (f32x4){0.f, 0.f, 0.f, 0.f};
  }
  float mrun[2] = {-INFINITY, -INFINITY};

  const short8 ONES = {0x3F80, 0x3F80, 0x3F80, 0x3F80,
                       0x3F80, 0x3F80, 0x3F80, 0x3F80};  // bf16 1.0 x8

  auto loadtile = [&](int kt, short8 kf[2][2], short8 vf[4]) {
#pragma unroll
    for (int t = 0; t < 2; ++t) {
      const u16* kr = Kp + (size_t)(kt + keyperm + 4 * t) * 1024;
#pragma unroll
      for (int hf = 0; hf < 2; ++hf)
        kf[t][hf] = *(const short8*)&kr[hf * 32 + g * 8];
    }
#pragma unroll
    for (int dg = 0; dg < 4; ++dg)
      vf[dg] = *(const short8*)&Vp[(size_t)(dg * 16 + rl) * 2048 + kt + g * 8];
  };

  auto process = [&](const short8 kf[2][2], const short8 vf[4]) {
    f32x4 sc[2][2];
#pragma unroll
    for (int qg = 0; qg < 2; ++qg)
#pragma unroll
      for (int t = 0; t < 2; ++t) {
        f32x4 a = (f32x4){0.f, 0.f, 0.f, 0.f};
        a = mfma_bf16(kf[t][0], qf[qg][0], a);
        a = mfma_bf16(kf[t][1], qf[qg][1], a);
        sc[qg][t] = a;
      }

    short8 pb[2];
#pragma unroll
    for (int qg = 0; qg < 2; ++qg) {
      float p2[8];
#pragma unroll
      for (int t = 0; t < 2; ++t)
#pragma unroll
        for (int r = 0; r < 4; ++r) p2[t * 4 + r] = sc[qg][t][r];
      // local max tree (max3-fusable)
      float a0 = fmaxf(fmaxf(p2[0], p2[1]), p2[2]);
      float a1 = fmaxf(fmaxf(p2[3], p2[4]), p2[5]);
      float a2 = fmaxf(p2[6], p2[7]);
      float tm = fmaxf(fmaxf(a0, a1), a2);
      // defer-max: only rescale when tile max grows past THR=8 (exp2 domain)
      if (!__all(tm <= mrun[qg] + 8.0f)) {
        tm = fmaxf(tm, __shfl_xor(tm, 16));
        tm = fmaxf(tm, __shfl_xor(tm, 32));
        float mnew = fmaxf(mrun[qg], tm);
        float sfac = __builtin_amdgcn_exp2f(mrun[qg] - mnew);
        mrun[qg] = mnew;
#pragma unroll
        for (int dg = 0; dg < 4; ++dg)
#pragma unroll
          for (int r = 0; r < 4; ++r) oacc[qg][dg][r] *= sfac;
        lacc[qg][0] *= sfac;   // only reg 0 is ever read
      }
      short8 pk;
#pragma unroll
      for (int j = 0; j < 8; ++j)
        pk[j] = (short)f2bf(__builtin_amdgcn_exp2f(p2[j] - mrun[qg]));
      pb[qg] = pk;
      lacc[qg] = mfma_bf16(ONES, pb[qg], lacc[qg]);   // row-sum on matrix pipe
    }
#pragma unroll
    for (int dg = 0; dg < 4; ++dg)
#pragma unroll
      for (int qg = 0; qg < 2; ++qg)
        oacc[qg][dg] = mfma_bf16(vf[dg], pb[qg], oacc[qg][dg]);
  };

  // register ping-pong double buffer over 64 tiles of 32 keys
  short8 kfA[2][2], vfA[4], kfB[2][2], vfB[4];
  loadtile(0, kfA, vfA);
  for (int kt = 0; kt < 2048; kt += 64) {
    loadtile((kt + 32) & 2047, kfB, vfB);   // wrap-masked: tail prefetch is unused
    process(kfA, vfA);
    loadtile((kt + 64) & 2047, kfA, vfA);
    process(kfB, vfB);
  }

#pragma unroll
  for (int qg = 0; qg < 2; ++qg) {
    float inv = 1.0f / lacc[qg][0];
    int qrow = qbase + qg * 16 + rl;
    u16* op = O + (size_t)(b * 2048 + qrow) * 1024 + h * 64;
#pragma unroll
    for (int dg = 0; dg < 4; ++dg) {
      u16x4 pk;
#pragma unroll
      for (int r = 0; r < 4; ++r) pk[r] = f2bf(oacc[qg][dg][r] * inv);
      *(u16x4*)&op[dg * 16 + g * 4] = pk;
    }
  }
}

// ---------------------------------------------------------------- launch
extern "C" void kernel_launch(void* const* d_in, const int* in_sizes, int n_in,
                              void* d_out, int out_size, void* d_ws, size_t ws_size,
                              hipStream_t stream) {
  const float* x  = (const float*)d_in[0];
  const float* Wq = (const float*)d_in[1];
  const float* bq = (const float*)d_in[2];
  const float* Wk = (const float*)d_in[3];
  const float* bk = (const float*)d_in[4];
  const float* Wv = (const float*)d_in[5];
  const float* bv = (const float*)d_in[6];
  const float* Wo = (const float*)d_in[7];
  const float* bo = (const float*)d_in[8];

  char* ws = (char*)d_ws;
  const size_t MB = 1024 * 1024;
  u16* Xb  = (u16*)(ws + 0 * MB);
  u16* Wqb = (u16*)(ws + 8 * MB);
  u16* Wkb = (u16*)(ws + 10 * MB);
  u16* Wvb = (u16*)(ws + 12 * MB);
  u16* Wob = (u16*)(ws + 14 * MB);
  u16* Qb  = (u16*)(ws + 16 * MB);
  u16* Kb  = (u16*)(ws + 24 * MB);
  u16* Vtb = (u16*)(ws + 32 * MB);
  u16* Ob  = (u16*)(ws + 40 * MB);

  cast_all<<<dim3(4096, 1, 5), 256, 0, stream>>>(x, Wq, Wk, Wv, Wo,
                                                 Xb, Wqb, Wkb, Wvb, Wob);
  gemm_qkv<<<dim3(8, 32, 3), 256, 0, stream>>>(Xb, Wqb, Wkb, Wvb,
                                               bq, bk, bv, Qb, Kb, Vtb);
  attn_fwd<<<dim3(16, 32), 256, 0, stream>>>(Qb, Kb, Vtb, Ob);
  gemm_out<<<dim3(8, 32), 256, 0, stream>>>(Ob, Wob, bo, (float*)d_out);
}

// Round 3
// 189.045 us; speedup vs baseline: 1.0853x; 1.0033x over previous
//
#include <hip/hip_runtime.h>
#include <hip/hip_bf16.h>

// MultiHeadAttention fused pipeline, round 3: XCD-resident K/V for attention.
// B=2 S=2048 D=1024 H=16 dk=64.
// ws layout (48 MB): Xb 8M | Wq/Wk/Wv/Wo bf16 2M each | Qb 8M | Kb 8M | Vt 8M | Ob 8M
// Changes vs R2:
//  - attn grid flattened to 512 blocks with XCD-aware mapping: block b -> XCD (b&7)
//    (hardware round-robin), XCD x owns bh in {4x..4x+3} -> 2MB K/V per XCD L2
//  - s_setprio(1) around attn MFMA clusters (T5; waves are independent here)

typedef unsigned short u16;
typedef __attribute__((ext_vector_type(4))) unsigned short u16x4;
typedef __attribute__((ext_vector_type(8))) short short8;   // 8 x bf16 (4 VGPRs)
typedef __attribute__((ext_vector_type(4))) float f32x4;

__device__ __forceinline__ u16 f2bf(float f) {  // native RNE f32->bf16
  __bf16 b = (__bf16)f;
  return __builtin_bit_cast(unsigned short, b);
}

__device__ __forceinline__ f32x4 mfma_bf16(short8 a, short8 b, f32x4 c) {
  return __builtin_amdgcn_mfma_f32_16x16x32_bf16(a, b, c, 0, 0, 0);
}

#define GLL16(gp, lp) __builtin_amdgcn_global_load_lds( \
    (const __attribute__((address_space(1))) void*)(gp), \
    (__attribute__((address_space(3))) void*)(lp), 16, 0, 0)

#define QSCALE 0.18033688011112042f   /* 0.125 * log2(e) */

// ---------------------------------------------------------------- casts
__global__ __launch_bounds__(256) void cast_all(
    const float* __restrict__ x,
    const float* __restrict__ wq, const float* __restrict__ wk,
    const float* __restrict__ wv, const float* __restrict__ wo,
    u16* __restrict__ xb, u16* __restrict__ wqb, u16* __restrict__ wkb,
    u16* __restrict__ wvb, u16* __restrict__ wob)
{
  const int z = blockIdx.z;
  const float* s; u16* d; int n4;
  if (z == 0)      { s = x;  d = xb;  n4 = 1048576; }
  else if (z == 1) { s = wq; d = wqb; n4 = 262144; }
  else if (z == 2) { s = wk; d = wkb; n4 = 262144; }
  else if (z == 3) { s = wv; d = wvb; n4 = 262144; }
  else             { s = wo; d = wob; n4 = 262144; }
  int i = blockIdx.x * 256 + threadIdx.x;
  if (i >= n4) return;
  float4 v = ((const float4*)s)[i];
  u16x4 o; o[0] = f2bf(v.x); o[1] = f2bf(v.y); o[2] = f2bf(v.z); o[3] = f2bf(v.w);
  ((u16x4*)d)[i] = o;
}

// -------------------------------------------------- 128x128 GEMM core, C = A * B^T
__device__ __forceinline__ void gemm_core(const u16* __restrict__ A,
                                          const u16* __restrict__ B,
                                          u16* sA, u16* sB, f32x4 acc[4][4])
{
  const int tid = threadIdx.x;
  const int lane = tid & 63, wave = tid >> 6;
  const int wr = wave >> 1, wc = wave & 1;
  const int m0 = blockIdx.y * 128, n0 = blockIdx.x * 128;
  const u16* ga = A + (size_t)(m0 + (tid >> 2)) * 1024 + (tid & 3) * 8;
  const u16* gb = B + (size_t)(n0 + (tid >> 2)) * 1024 + (tid & 3) * 8;
  u16* la0 = sA + wave * 512;          u16* la1 = sA + 2048 + wave * 512;
  u16* lb0 = sB + wave * 512;          u16* lb1 = sB + 2048 + wave * 512;
  const int rl = lane & 15, kg = (lane >> 4) * 8;

  for (int k0 = 0; k0 < 1024; k0 += 32) {
    GLL16(ga + k0,             la0);
    GLL16(ga + 64 * 1024 + k0, la1);
    GLL16(gb + k0,             lb0);
    GLL16(gb + 64 * 1024 + k0, lb1);
    __syncthreads();
    short8 af[4], bf_[4];
#pragma unroll
    for (int m = 0; m < 4; ++m) af[m]  = *(const short8*)&sA[(wr * 64 + m * 16 + rl) * 32 + kg];
#pragma unroll
    for (int n = 0; n < 4; ++n) bf_[n] = *(const short8*)&sB[(wc * 64 + n * 16 + rl) * 32 + kg];
#pragma unroll
    for (int m = 0; m < 4; ++m)
#pragma unroll
      for (int n = 0; n < 4; ++n)
        acc[m][n] = mfma_bf16(af[m], bf_[n], acc[m][n]);
    __syncthreads();
  }
}

// QKV projections fused via blockIdx.z. z=0 -> Q (PRE-SCALED by QSCALE),
// z=1 -> K, z=2 -> V written TRANSPOSED: Vt[(b*1024+hd)][s].
__global__ __launch_bounds__(256) void gemm_qkv(
    const u16* __restrict__ X,
    const u16* __restrict__ Wqb, const u16* __restrict__ Wkb, const u16* __restrict__ Wvb,
    const float* __restrict__ bq, const float* __restrict__ bk, const float* __restrict__ bv,
    u16* __restrict__ Qo, u16* __restrict__ Ko, u16* __restrict__ Vt)
{
  __shared__ u16 sA[4096], sB[4096];
  const int z = blockIdx.z;
  const u16* W = (z == 0) ? Wqb : (z == 1) ? Wkb : Wvb;
  const float* bias = (z == 0) ? bq : (z == 1) ? bk : bv;

  f32x4 acc[4][4];
#pragma unroll
  for (int m = 0; m < 4; ++m)
#pragma unroll
    for (int n = 0; n < 4; ++n) acc[m][n] = (f32x4){0.f, 0.f, 0.f, 0.f};

  gemm_core(X, W, sA, sB, acc);

  const int lane = threadIdx.x & 63, wave = threadIdx.x >> 6;
  const int wr = wave >> 1, wc = wave & 1;
  const int m0 = blockIdx.y * 128, n0 = blockIdx.x * 128;
  const int rl = lane & 15, rg = (lane >> 4) * 4;

  if (z < 2) {
    u16* dst = (z == 0) ? Qo : Ko;
    const float cs = (z == 0) ? QSCALE : 1.0f;
#pragma unroll
    for (int n = 0; n < 4; ++n) {
      int col = n0 + wc * 64 + n * 16 + rl;
      float bb = bias[col];
#pragma unroll
      for (int m = 0; m < 4; ++m) {
        int row0 = m0 + wr * 64 + m * 16 + rg;
#pragma unroll
        for (int r = 0; r < 4; ++r)
          dst[(size_t)(row0 + r) * 1024 + col] = f2bf((acc[m][n][r] + bb) * cs);
      }
    }
  } else {
#pragma unroll
    for (int n = 0; n < 4; ++n) {
      int col = n0 + wc * 64 + n * 16 + rl;   // hd = h*64+d
      float bb = bias[col];
#pragma unroll
      for (int m = 0; m < 4; ++m) {
        int row0 = m0 + wr * 64 + m * 16 + rg;          // b*2048 + s
        int bidx = row0 >> 11, sl = row0 & 2047;
        u16x4 pk;
#pragma unroll
        for (int r = 0; r < 4; ++r) pk[r] = f2bf(acc[m][n][r] + bb);
        *(u16x4*)&Vt[((size_t)(bidx * 1024 + col)) * 2048 + sl] = pk;
      }
    }
  }
}

// Output projection: out(fp32) = Ob @ Wo^T + bo
__global__ __launch_bounds__(256) void gemm_out(
    const u16* __restrict__ Ob, const u16* __restrict__ Wob,
    const float* __restrict__ bo, float* __restrict__ Out)
{
  __shared__ u16 sA[4096], sB[4096];
  f32x4 acc[4][4];
#pragma unroll
  for (int m = 0; m < 4; ++m)
#pragma unroll
    for (int n = 0; n < 4; ++n) acc[m][n] = (f32x4){0.f, 0.f, 0.f, 0.f};

  gemm_core(Ob, Wob, sA, sB, acc);

  const int lane = threadIdx.x & 63, wave = threadIdx.x >> 6;
  const int wr = wave >> 1, wc = wave & 1;
  const int m0 = blockIdx.y * 128, n0 = blockIdx.x * 128;
  const int rl = lane & 15, rg = (lane >> 4) * 4;
#pragma unroll
  for (int n = 0; n < 4; ++n) {
    int col = n0 + wc * 64 + n * 16 + rl;
    float bb = bo[col];
#pragma unroll
    for (int m = 0; m < 4; ++m) {
      int row0 = m0 + wr * 64 + m * 16 + rg;
#pragma unroll
      for (int r = 0; r < 4; ++r)
        Out[(size_t)(row0 + r) * 1024 + col] = acc[m][n][r] + bb;
    }
  }
}

// ---------------------------------------------------------------- flash attention
// Swapped QK^T (mfma(K,Q)): lane owns one q-column, 8 keys per tile.
// K rows loaded PERMUTED so score C-regs are exactly the PV B-operand k-order.
// Q pre-scaled by 0.125*log2e -> scores already in exp2 domain.
// Grid: 512 blocks flat. Block b runs on XCD (b&7) [HW round-robin]; XCD x
// owns bh in {4x..4x+3} -> 4 x 512KB K/V working set fits its 4MB L2.
__global__ __launch_bounds__(256) void attn_fwd(
    const u16* __restrict__ Q, const u16* __restrict__ K,
    const u16* __restrict__ Vt, u16* __restrict__ O)
{
  const int tid = threadIdx.x, lane = tid & 63, wave = tid >> 6;
  const int rl = lane & 15, g = lane >> 4;

  const int bflat = blockIdx.x;
  const int xcd = bflat & 7, j = bflat >> 3;        // 512 = 8 XCD * 64
  const int bh = xcd * 4 + (j >> 4);                // 4 bh per XCD
  const int qchunk = j & 15;
  const int b = bh >> 4, h = bh & 15;
  const int qbase = qchunk * 128 + wave * 32;

  const u16* Qp = Q + (size_t)(b * 2048 + qbase) * 1024 + h * 64;
  const u16* Kp = K + (size_t)(b * 2048) * 1024 + h * 64;
  const u16* Vp = Vt + (size_t)(bh * 64) * 2048;

  short8 qf[2][2];
#pragma unroll
  for (int qg = 0; qg < 2; ++qg)
#pragma unroll
    for (int hf = 0; hf < 2; ++hf)
      qf[qg][hf] = *(const short8*)&Qp[(size_t)(qg * 16 + rl) * 1024 + hf * 32 + g * 8];

  const int keyperm = 8 * (rl >> 2) + (rl & 3);

  f32x4 oacc[2][4];
  f32x4 lacc[2];
#pragma unroll
  for (int qg = 0; qg < 2; ++qg) {
    lacc[qg] = (f32x4){0.f, 0.f, 0.f, 0.f};
#pragma unroll
    for (int dg = 0; dg < 4; ++dg) oacc[qg][dg] = (f32x4){0.f, 0.f, 0.f, 0.f};
  }
  float mrun[2] = {-INFINITY, -INFINITY};

  const short8 ONES = {0x3F80, 0x3F80, 0x3F80, 0x3F80,
                       0x3F80, 0x3F80, 0x3F80, 0x3F80};  // bf16 1.0 x8

  auto loadtile = [&](int kt, short8 kf[2][2], short8 vf[4]) {
#pragma unroll
    for (int t = 0; t < 2; ++t) {
      const u16* kr = Kp + (size_t)(kt + keyperm + 4 * t) * 1024;
#pragma unroll
      for (int hf = 0; hf < 2; ++hf)
        kf[t][hf] = *(const short8*)&kr[hf * 32 + g * 8];
    }
#pragma unroll
    for (int dg = 0; dg < 4; ++dg)
      vf[dg] = *(const short8*)&Vp[(size_t)(dg * 16 + rl) * 2048 + kt + g * 8];
  };

  auto process = [&](const short8 kf[2][2], const short8 vf[4]) {
    f32x4 sc[2][2];
    __builtin_amdgcn_s_setprio(1);
#pragma unroll
    for (int qg = 0; qg < 2; ++qg)
#pragma unroll
      for (int t = 0; t < 2; ++t) {
        f32x4 a = (f32x4){0.f, 0.f, 0.f, 0.f};
        a = mfma_bf16(kf[t][0], qf[qg][0], a);
        a = mfma_bf16(kf[t][1], qf[qg][1], a);
        sc[qg][t] = a;
      }
    __builtin_amdgcn_s_setprio(0);

    short8 pb[2];
#pragma unroll
    for (int qg = 0; qg < 2; ++qg) {
      float p2[8];
#pragma unroll
      for (int t = 0; t < 2; ++t)
#pragma unroll
        for (int r = 0; r < 4; ++r) p2[t * 4 + r] = sc[qg][t][r];
      // local max tree (max3-fusable)
      float a0 = fmaxf(fmaxf(p2[0], p2[1]), p2[2]);
      float a1 = fmaxf(fmaxf(p2[3], p2[4]), p2[5]);
      float a2 = fmaxf(p2[6], p2[7]);
      float tm = fmaxf(fmaxf(a0, a1), a2);
      // defer-max: only rescale when tile max grows past THR=8 (exp2 domain)
      if (!__all(tm <= mrun[qg] + 8.0f)) {
        tm = fmaxf(tm, __shfl_xor(tm, 16));
        tm = fmaxf(tm, __shfl_xor(tm, 32));
        float mnew = fmaxf(mrun[qg], tm);
        float sfac = __builtin_amdgcn_exp2f(mrun[qg] - mnew);
        mrun[qg] = mnew;
#pragma unroll
        for (int dg = 0; dg < 4; ++dg)
#pragma unroll
          for (int r = 0; r < 4; ++r) oacc[qg][dg][r] *= sfac;
        lacc[qg][0] *= sfac;   // only reg 0 is ever read
      }
      short8 pk;
#pragma unroll
      for (int j2 = 0; j2 < 8; ++j2)
        pk[j2] = (short)f2bf(__builtin_amdgcn_exp2f(p2[j2] - mrun[qg]));
      pb[qg] = pk;
      lacc[qg] = mfma_bf16(ONES, pb[qg], lacc[qg]);   // row-sum on matrix pipe
    }
    __builtin_amdgcn_s_setprio(1);
#pragma unroll
    for (int dg = 0; dg < 4; ++dg)
#pragma unroll
      for (int qg = 0; qg < 2; ++qg)
        oacc[qg][dg] = mfma_bf16(vf[dg], pb[qg], oacc[qg][dg]);
    __builtin_amdgcn_s_setprio(0);
  };

  // register ping-pong double buffer over 64 tiles of 32 keys
  short8 kfA[2][2], vfA[4], kfB[2][2], vfB[4];
  loadtile(0, kfA, vfA);
  for (int kt = 0; kt < 2048; kt += 64) {
    loadtile((kt + 32) & 2047, kfB, vfB);   // wrap-masked: tail prefetch is unused
    process(kfA, vfA);
    loadtile((kt + 64) & 2047, kfA, vfA);
    process(kfB, vfB);
  }

#pragma unroll
  for (int qg = 0; qg < 2; ++qg) {
    float inv = 1.0f / lacc[qg][0];
    int qrow = qbase + qg * 16 + rl;
    u16* op = O + (size_t)(b * 2048 + qrow) * 1024 + h * 64;
#pragma unroll
    for (int dg = 0; dg < 4; ++dg) {
      u16x4 pk;
#pragma unroll
      for (int r = 0; r < 4; ++r) pk[r] = f2bf(oacc[qg][dg][r] * inv);
      *(u16x4*)&op[dg * 16 + g * 4] = pk;
    }
  }
}

// ---------------------------------------------------------------- launch
extern "C" void kernel_launch(void* const* d_in, const int* in_sizes, int n_in,
                              void* d_out, int out_size, void* d_ws, size_t ws_size,
                              hipStream_t stream) {
  const float* x  = (const float*)d_in[0];
  const float* Wq = (const float*)d_in[1];
  const float* bq = (const float*)d_in[2];
  const float* Wk = (const float*)d_in[3];
  const float* bk = (const float*)d_in[4];
  const float* Wv = (const float*)d_in[5];
  const float* bv = (const float*)d_in[6];
  const float* Wo = (const float*)d_in[7];
  const float* bo = (const float*)d_in[8];

  char* ws = (char*)d_ws;
  const size_t MB = 1024 * 1024;
  u16* Xb  = (u16*)(ws + 0 * MB);
  u16* Wqb = (u16*)(ws + 8 * MB);
  u16* Wkb = (u16*)(ws + 10 * MB);
  u16* Wvb = (u16*)(ws + 12 * MB);
  u16* Wob = (u16*)(ws + 14 * MB);
  u16* Qb  = (u16*)(ws + 16 * MB);
  u16* Kb  = (u16*)(ws + 24 * MB);
  u16* Vtb = (u16*)(ws + 32 * MB);
  u16* Ob  = (u16*)(ws + 40 * MB);

  cast_all<<<dim3(4096, 1, 5), 256, 0, stream>>>(x, Wq, Wk, Wv, Wo,
                                                 Xb, Wqb, Wkb, Wvb, Wob);
  gemm_qkv<<<dim3(8, 32, 3), 256, 0, stream>>>(Xb, Wqb, Wkb, Wvb,
                                               bq, bk, bv, Qb, Kb, Vtb);
  attn_fwd<<<dim3(512), 256, 0, stream>>>(Qb, Kb, Vtb, Ob);
  gemm_out<<<dim3(8, 32), 256, 0, stream>>>(Ob, Wob, bo, (float*)d_out);
}